// Round 7
// baseline (132.729 us; speedup 1.0000x reference)
//
#include <hip/hip_runtime.h>
#include <hip/hip_bf16.h>
#include <math.h>

#define BB 2
#define NN 16384
#define KK 16
#define CC 128
#define COUT 128
#define NODES (BB * NN)
#define SP 136   // bf16 staging row pitch (elements; 272 B -> 16B-aligned rows)
#define SQP 136  // fp8 staging row pitch (bytes)
#define ZP 136   // z-tile row pitch (elements)
#define XBLK 2048

typedef __attribute__((ext_vector_type(8))) short bf16x8;
typedef __attribute__((ext_vector_type(4))) float f32x4;
typedef __attribute__((ext_vector_type(2))) float f32x2;  // matches fp8 builtin returns

__device__ __forceinline__ bf16x8 cvt8(f32x4 a, f32x4 b) {
    union { bf16x8 v; __hip_bfloat162 h[4]; } u;
    u.h[0] = __float22bfloat162_rn(make_float2(a[0], a[1]));
    u.h[1] = __float22bfloat162_rn(make_float2(a[2], a[3]));
    u.h[2] = __float22bfloat162_rn(make_float2(b[0], b[1]));
    u.h[3] = __float22bfloat162_rn(make_float2(b[2], b[3]));
    return u.v;
}

// fp8x8 (int2) -> bf16x8
__device__ __forceinline__ bf16x8 up8(int2 wb) {
    f32x2 f0 = __builtin_amdgcn_cvt_pk_f32_fp8(wb.x, false);
    f32x2 f1 = __builtin_amdgcn_cvt_pk_f32_fp8(wb.x, true);
    f32x2 f2 = __builtin_amdgcn_cvt_pk_f32_fp8(wb.y, false);
    f32x2 f3 = __builtin_amdgcn_cvt_pk_f32_fp8(wb.y, true);
    union { bf16x8 v; __hip_bfloat162 h[4]; } u;
    u.h[0] = __float22bfloat162_rn(make_float2(f0[0], f0[1]));
    u.h[1] = __float22bfloat162_rn(make_float2(f1[0], f1[1]));
    u.h[2] = __float22bfloat162_rn(make_float2(f2[0], f2[1]));
    u.h[3] = __float22bfloat162_rn(make_float2(f3[0], f3[1]));
    return u.v;
}

// DPP row_ror adds within each 16-lane row (VALU pipe).
template <int CTRL>
__device__ __forceinline__ float rot_add(float v) {
    int r = __builtin_amdgcn_update_dpp(0, __float_as_int(v), CTRL, 0xF, 0xF, true);
    return v + __int_as_float(r);
}
__device__ __forceinline__ float row16_sum(float v) {
    v = rot_add<0x128>(v); v = rot_add<0x124>(v);
    v = rot_add<0x122>(v); v = rot_add<0x121>(v);
    return v;
}

// ---------------------------------------------------------------------------
// Kernel P: x (fp32) -> xh (bf16) + xq (fp8 e4m3), streaming. 8 elems/thread.
// Tail blocks cast W fp32 -> wh bf16 (same cvt8 rounding as before).
// ---------------------------------------------------------------------------
__global__ __launch_bounds__(256) void cast_x(
    const float* __restrict__ x,
    __hip_bfloat16* __restrict__ xh,
    unsigned char* __restrict__ xq,
    const float* __restrict__ W,
    __hip_bfloat16* __restrict__ wh)
{
    const int bid = blockIdx.x;
    if (bid >= XBLK) {
        const int i = (bid - XBLK) * 256 + threadIdx.x;
        const f32x4* p = (const f32x4*)(W + (size_t)i * 8);
        f32x4 a = p[0];
        f32x4 b = p[1];
        *(bf16x8*)(wh + (size_t)i * 8) = cvt8(a, b);
        return;
    }
    const int i = bid * 256 + threadIdx.x;
    const f32x4* p = (const f32x4*)(x + (size_t)i * 8);
    f32x4 a = __builtin_nontemporal_load(p);
    f32x4 b = __builtin_nontemporal_load(p + 1);
    *(bf16x8*)(xh + (size_t)i * 8) = cvt8(a, b);
    int lo = __builtin_amdgcn_cvt_pk_fp8_f32(a[0], a[1], 0, false);
    lo     = __builtin_amdgcn_cvt_pk_fp8_f32(a[2], a[3], lo, true);
    int hi = __builtin_amdgcn_cvt_pk_fp8_f32(b[0], b[1], 0, false);
    hi     = __builtin_amdgcn_cvt_pk_fp8_f32(b[2], b[3], hi, true);
    int2 v; v.x = lo; v.y = hi;
    *(int2*)(xq + (size_t)i * 8) = v;
}

// Softmax column-sum: scores (C-layout) -> w for this lane's Xj row m.
__device__ __forceinline__ float col_weight(f32x4 acc) {
    const float scale = 0.08838834764831843f;  // 1/sqrt(128)
    float w = 0.f;
    #pragma unroll
    for (int i = 0; i < 4; ++i) {
        float e = __expf(acc[i] * scale);
        float s = row16_sum(e);
        w += e * __builtin_amdgcn_rcpf(s);
    }
    w += __shfl_xor(w, 16, 64);
    w += __shfl_xor(w, 32, 64);
    return w;
}

struct Rows { int2 qi[4]; bf16x8 j[4]; };

// Staged-gather shape (R0-proven): Xi fp8 4 inst x (4 rows x 128B),
// Xj bf16 4 inst x (4 rows x 256B) — few LONG segments per instruction
// (R1's fragment-order gathers regressed 11.5us: TA/transaction-bound path).
// Edge indices pre-hoisted in m-layout regs; redistributed via __shfl.
__device__ __forceinline__ void gather_rows(
    int ejv, int eiv, int r, int c,
    const __hip_bfloat16* __restrict__ xbh,
    const unsigned char* __restrict__ xbq,
    Rows& g)
{
    #pragma unroll
    for (int gg = 0; gg < 4; ++gg) {
        int ri = __shfl(eiv, gg * 4 + r, 16);
        g.qi[gg] = *(const int2*)(xbq + (size_t)ri * CC + c * 8);
    }
    #pragma unroll
    for (int gg = 0; gg < 4; ++gg) {
        int rj = __shfl(ejv, gg * 4 + r, 16);
        g.j[gg] = *(const bf16x8*)(xbh + (size_t)rj * CC + c * 8);
    }
}

// ---------------------------------------------------------------------------
// Fused kernel: block = 16 nodes (4 waves x 4 nodes serial), z tile in LDS,
// then the 16x128 @ 128x128 linear. This round: 2-DEEP gather prefetch.
// R5/R6 counters: latency-bound (HBM 14%, MFMA 2%, VALU 35%, occ 37%;
// VALU-reduction was neutral). With 1-deep prefetch, stall/node ~= L - C
// (~500cy at L~900, C~400). 3 rotating buffers (A,B,C) keep 16 row-gather
// loads in flight per wave; staging node `it` waits only on A's loads
// (counted vmcnt, B+C outstanding) -> stall ~= L - 2C ~= 100cy.
// C's gathers issue at the TOP of the loop body to maximize the window.
// VGPR: 3x24 buffers + ~24 working ~= 96 <= 102 (5 blk/CU ceiling), pinned
// by __launch_bounds__(256,5). LDS unchanged 30464 B.
// ---------------------------------------------------------------------------
__global__ __launch_bounds__(256, 5) void attn_fused(
    const __hip_bfloat16* __restrict__ xh,
    const unsigned char* __restrict__ xq,
    const int* __restrict__ edge,
    const __hip_bfloat16* __restrict__ wh,
    const float* __restrict__ bias,
    float* __restrict__ out)
{
    __shared__ alignas(16) __hip_bfloat16 stgj[4][16 * SP];  // Xj bf16
    __shared__ alignas(16) unsigned char stgq[4][16 * SQP];  // Xi fp8 (+w corner)
    __shared__ alignas(16) __hip_bfloat16 zt[16][ZP];        // z tile

    const int t = threadIdx.x;
    const int wv = t >> 6;
    const int lane = t & 63;
    const int m = lane & 15;   // fragment row
    const int q = lane >> 4;   // fragment k-quad
    const int r = lane >> 4;   // staging: row-in-group 0..3
    const int c = lane & 15;   // staging: chunk within row
    const int base = blockIdx.x * 16;
    const int node0 = base + wv * 4;
    const int b = node0 >> 14;          // block of 16 nodes never straddles NN

    const __hip_bfloat16* xbh = xh + (size_t)b * (size_t)(NN * CC);
    const unsigned char*  xbq = xq + (size_t)b * (size_t)(NN * CC);
    __hip_bfloat16* sj = &stgj[wv][0];
    unsigned char*  sq = &stgq[wv][0];
    float*          wb16 = (float*)sq;  // 64B w-broadcast corner (aliased)

    // ---- hoisted edge indices (m-layout) + residual rows for all 4 nodes ----
    int ejv[4], eiv[4];
    __hip_bfloat162 rxv[4];
    #pragma unroll
    for (int n = 0; n < 4; ++n) {
        const int* ej = edge + (size_t)(node0 + n) * KK;
        ejv[n] = __builtin_nontemporal_load(ej + m);
        eiv[n] = __builtin_nontemporal_load(ej + (size_t)NODES * KK + m);
        const int nloc = (node0 + n) & (NN - 1);
        rxv[n] = *(const __hip_bfloat162*)(xbh + (size_t)nloc * CC + 2 * lane);
    }

    // ---- 2-deep prefetch: A=cur, B=next, C=next+1 (rotated, fully unrolled)
    Rows A, B, C;
    gather_rows(ejv[0], eiv[0], r, c, xbh, xbq, A);
    gather_rows(ejv[1], eiv[1], r, c, xbh, xbq, B);

    #pragma unroll
    for (int it = 0; it < 4; ++it) {
        // ---- issue node it+2's gathers first (no wait needed; max window) ----
        if (it < 2)
            gather_rows(ejv[it + 2], eiv[it + 2], r, c, xbh, xbq, C);

        // ---- stage node it to LDS (counted wait on A only; B,C in flight) ----
        #pragma unroll
        for (int g = 0; g < 4; ++g)
            *(int2*)(sq + (g * 4 + r) * SQP + c * 8) = A.qi[g];
        #pragma unroll
        for (int g = 0; g < 4; ++g)
            *(bf16x8*)(sj + (g * 4 + r) * SP + c * 8) = A.j[g];

        // ---- fragments + scores; Xi fp8->bf16 fused into MFMA loop ----
        f32x4 acc = {0.f, 0.f, 0.f, 0.f};
        #pragma unroll
        for (int s = 0; s < 4; ++s) {
            int2 wa = *(const int2*)(sq + m * SQP + s * 32 + q * 8);
            bf16x8 bfr = *(const bf16x8*)(sj + m * SP + s * 32 + q * 8);
            acc = __builtin_amdgcn_mfma_f32_16x16x32_bf16(up8(wa), bfr, acc, 0, 0, 0);
        }

        // ---- softmax col-sum: wj for j = lane&15, replicated over q ----
        const float wj = col_weight(acc);

        // ---- h via column reduction: broadcast w, then each lane fmas its
        //      own 2 channels from Xj columns (sq consumed; corner aliased) ----
        if (lane < 16) wb16[lane] = wj;
        f32x4 wv0 = *(const f32x4*)&wb16[0];
        f32x4 wv1 = *(const f32x4*)&wb16[4];
        f32x4 wv2 = *(const f32x4*)&wb16[8];
        f32x4 wv3 = *(const f32x4*)&wb16[12];
        float wvv[16] = {wv0[0], wv0[1], wv0[2], wv0[3],
                         wv1[0], wv1[1], wv1[2], wv1[3],
                         wv2[0], wv2[1], wv2[2], wv2[3],
                         wv3[0], wv3[1], wv3[2], wv3[3]};
        float ax[4] = {0.f, 0.f, 0.f, 0.f};
        float ay[4] = {0.f, 0.f, 0.f, 0.f};
        const char* sjb = (const char*)sj + 4 * lane;
        #pragma unroll
        for (int j = 0; j < 16; ++j) {
            unsigned u = *(const unsigned*)(sjb + j * (SP * 2));
            float lo = __uint_as_float(u << 16);
            float hi = __uint_as_float(u & 0xffff0000u);
            ax[j & 3] = fmaf(wvv[j], lo, ax[j & 3]);
            ay[j & 3] = fmaf(wvv[j], hi, ay[j & 3]);
        }
        float hx = (ax[0] + ax[1]) + (ax[2] + ax[3]);
        float hy = (ay[0] + ay[1]) + (ay[2] + ay[3]);

        // ---- residual + cast, into the z LDS tile ----
        float2 xc = __bfloat1622float2(rxv[it]);
        const int row = wv * 4 + it;
        *(__hip_bfloat162*)(&zt[row][2 * lane]) =
            __float22bfloat162_rn(make_float2(xc.x + hx, xc.y + hy));

        // ---- rotate buffers (SSA renames under full unroll; no movs) ----
        A = B; B = C;
    }

    __syncthreads();

    // ---- fused linear: out[16 nodes][128] = relu(zt @ W^T + b) ----
    bf16x8 zfr[4];
    #pragma unroll
    for (int s = 0; s < 4; ++s)
        zfr[s] = *(const bf16x8*)(&zt[m][s * 32 + q * 8]);

    #pragma unroll
    for (int half = 0; half < 2; ++half) {
        const int ct = wv * 2 + half;            // cout-tile 0..7
        const __hip_bfloat16* wp = wh + (size_t)(ct * 16 + m) * CC + q * 8;
        bf16x8 wfr[4];
        #pragma unroll
        for (int s = 0; s < 4; ++s)
            wfr[s] = *(const bf16x8*)(wp + s * 32);
        const float bv = bias[ct * 16 + m];
        f32x4 acc = {0.f, 0.f, 0.f, 0.f};
        #pragma unroll
        for (int s = 0; s < 4; ++s)
            acc = __builtin_amdgcn_mfma_f32_16x16x32_bf16(zfr[s], wfr[s], acc, 0, 0, 0);
        // C/D layout: col = lane&15 = cout-in-tile, row = q*4+i = node-in-tile
        float* op = out + (size_t)(base + q * 4) * COUT + ct * 16 + m;
        #pragma unroll
        for (int i = 0; i < 4; ++i)
            op[(size_t)i * COUT] = fmaxf(acc[i] + bv, 0.f);
    }
}

extern "C" void kernel_launch(void* const* d_in, const int* in_sizes, int n_in,
                              void* d_out, int out_size, void* d_ws, size_t ws_size,
                              hipStream_t stream) {
    const float* x    = (const float*)d_in[0];
    const int*   edge = (const int*)d_in[1];
    const float* W    = (const float*)d_in[2];
    const float* bias = (const float*)d_in[3];
    float* out = (float*)d_out;
    __hip_bfloat16* xh = (__hip_bfloat16*)d_ws;                              // 8 MB
    unsigned char*  xq = (unsigned char*)d_ws + 8 * 1024 * 1024;             // 4 MB
    __hip_bfloat16* wh = (__hip_bfloat16*)((char*)d_ws + 12 * 1024 * 1024);  // 32 KB

    cast_x<<<XBLK + (COUT * CC) / (256 * 8), 256, 0, stream>>>(x, xh, xq, W, wh);
    attn_fused<<<NODES / 16, 256, 0, stream>>>(xh, xq, edge, wh, bias, out);
}

// Round 8
// 102.884 us; speedup vs baseline: 1.2901x; 1.2901x over previous
//
#include <hip/hip_runtime.h>
#include <hip/hip_bf16.h>
#include <math.h>

#define BB 2
#define NN 16384
#define KK 16
#define CC 128
#define COUT 128
#define NODES (BB * NN)
#define SP 136   // bf16 staging row pitch (elements; 272 B -> 16B-aligned rows)
#define SQP 136  // fp8 staging row pitch (bytes)
#define ZP 136   // z-tile row pitch (elements)
#define XBLK 2048

typedef __attribute__((ext_vector_type(8))) short bf16x8;
typedef __attribute__((ext_vector_type(4))) float f32x4;
typedef __attribute__((ext_vector_type(2))) float f32x2;  // matches fp8 builtin returns

__device__ __forceinline__ bf16x8 cvt8(f32x4 a, f32x4 b) {
    union { bf16x8 v; __hip_bfloat162 h[4]; } u;
    u.h[0] = __float22bfloat162_rn(make_float2(a[0], a[1]));
    u.h[1] = __float22bfloat162_rn(make_float2(a[2], a[3]));
    u.h[2] = __float22bfloat162_rn(make_float2(b[0], b[1]));
    u.h[3] = __float22bfloat162_rn(make_float2(b[2], b[3]));
    return u.v;
}

// fp8x8 (int2) -> bf16x8
__device__ __forceinline__ bf16x8 up8(int2 wb) {
    f32x2 f0 = __builtin_amdgcn_cvt_pk_f32_fp8(wb.x, false);
    f32x2 f1 = __builtin_amdgcn_cvt_pk_f32_fp8(wb.x, true);
    f32x2 f2 = __builtin_amdgcn_cvt_pk_f32_fp8(wb.y, false);
    f32x2 f3 = __builtin_amdgcn_cvt_pk_f32_fp8(wb.y, true);
    union { bf16x8 v; __hip_bfloat162 h[4]; } u;
    u.h[0] = __float22bfloat162_rn(make_float2(f0[0], f0[1]));
    u.h[1] = __float22bfloat162_rn(make_float2(f1[0], f1[1]));
    u.h[2] = __float22bfloat162_rn(make_float2(f2[0], f2[1]));
    u.h[3] = __float22bfloat162_rn(make_float2(f3[0], f3[1]));
    return u.v;
}

// DPP row_ror adds within each 16-lane row (VALU pipe).
template <int CTRL>
__device__ __forceinline__ float rot_add(float v) {
    int r = __builtin_amdgcn_update_dpp(0, __float_as_int(v), CTRL, 0xF, 0xF, true);
    return v + __int_as_float(r);
}
__device__ __forceinline__ float row16_sum(float v) {
    v = rot_add<0x128>(v); v = rot_add<0x124>(v);
    v = rot_add<0x122>(v); v = rot_add<0x121>(v);
    return v;
}

// ---------------------------------------------------------------------------
// Kernel P: x (fp32) -> xh (bf16) + xq (fp8 e4m3), streaming. 8 elems/thread.
// Tail blocks cast W fp32 -> wh bf16 (same cvt8 rounding as before).
// ---------------------------------------------------------------------------
__global__ __launch_bounds__(256) void cast_x(
    const float* __restrict__ x,
    __hip_bfloat16* __restrict__ xh,
    unsigned char* __restrict__ xq,
    const float* __restrict__ W,
    __hip_bfloat16* __restrict__ wh)
{
    const int bid = blockIdx.x;
    if (bid >= XBLK) {
        const int i = (bid - XBLK) * 256 + threadIdx.x;
        const f32x4* p = (const f32x4*)(W + (size_t)i * 8);
        f32x4 a = p[0];
        f32x4 b = p[1];
        *(bf16x8*)(wh + (size_t)i * 8) = cvt8(a, b);
        return;
    }
    const int i = bid * 256 + threadIdx.x;
    const f32x4* p = (const f32x4*)(x + (size_t)i * 8);
    f32x4 a = __builtin_nontemporal_load(p);
    f32x4 b = __builtin_nontemporal_load(p + 1);
    *(bf16x8*)(xh + (size_t)i * 8) = cvt8(a, b);
    int lo = __builtin_amdgcn_cvt_pk_fp8_f32(a[0], a[1], 0, false);
    lo     = __builtin_amdgcn_cvt_pk_fp8_f32(a[2], a[3], lo, true);
    int hi = __builtin_amdgcn_cvt_pk_fp8_f32(b[0], b[1], 0, false);
    hi     = __builtin_amdgcn_cvt_pk_fp8_f32(b[2], b[3], hi, true);
    int2 v; v.x = lo; v.y = hi;
    *(int2*)(xq + (size_t)i * 8) = v;
}

// Softmax column-sum: scores (C-layout) -> w for this lane's Xj row m.
__device__ __forceinline__ float col_weight(f32x4 acc) {
    const float scale = 0.08838834764831843f;  // 1/sqrt(128)
    float w = 0.f;
    #pragma unroll
    for (int i = 0; i < 4; ++i) {
        float e = __expf(acc[i] * scale);
        float s = row16_sum(e);
        w += e * __builtin_amdgcn_rcpf(s);
    }
    w += __shfl_xor(w, 16, 64);
    w += __shfl_xor(w, 32, 64);
    return w;
}

struct Rows { int2 qi[4]; bf16x8 j[4]; };

// Staged-gather shape (R0-proven): Xi fp8 4 inst x (4 rows x 128B),
// Xj bf16 4 inst x (4 rows x 256B) — few LONG segments per instruction
// (R1's fragment-order gathers regressed 11.5us: TA/transaction-bound path).
// Edge indices pre-hoisted in m-layout regs; redistributed via __shfl.
__device__ __forceinline__ void gather_rows(
    int ejv, int eiv, int r, int c,
    const __hip_bfloat16* __restrict__ xbh,
    const unsigned char* __restrict__ xbq,
    Rows& g)
{
    #pragma unroll
    for (int gg = 0; gg < 4; ++gg) {
        int ri = __shfl(eiv, gg * 4 + r, 16);
        g.qi[gg] = *(const int2*)(xbq + (size_t)ri * CC + c * 8);
    }
    #pragma unroll
    for (int gg = 0; gg < 4; ++gg) {
        int rj = __shfl(ejv, gg * 4 + r, 16);
        g.j[gg] = *(const bf16x8*)(xbh + (size_t)rj * CC + c * 8);
    }
}

// ---------------------------------------------------------------------------
// Fused kernel: block = 16 nodes (4 waves x 4 nodes serial), z tile in LDS,
// then the 16x128 @ 128x128 linear. This round fixes R7's failure mode:
// the 2-deep prefetch SPILLED (WRITE_SIZE 22->94 MB) because
// __launch_bounds__(256,5) caps the allocator below the 64-VGPR HW step
// (m69: occupancy steps at 64/128/256) — 3x24-reg buffers couldn't live in
// 48 regs. Fix: (256,4) -> 128-VGPR budget, and HAND-PEELED iterations with
// distinct A,B,C0,C1 buffers (no conditional writes, no rotation copies —
// pure SSA). C0/C1 gathers still issue before staging A/B (max window).
// Peak live ~= 2 buffers (48) + working (~40) < 128. LDS unchanged 30464 B.
// ---------------------------------------------------------------------------
__global__ __launch_bounds__(256, 4) void attn_fused(
    const __hip_bfloat16* __restrict__ xh,
    const unsigned char* __restrict__ xq,
    const int* __restrict__ edge,
    const __hip_bfloat16* __restrict__ wh,
    const float* __restrict__ bias,
    float* __restrict__ out)
{
    __shared__ alignas(16) __hip_bfloat16 stgj[4][16 * SP];  // Xj bf16
    __shared__ alignas(16) unsigned char stgq[4][16 * SQP];  // Xi fp8 (+w corner)
    __shared__ alignas(16) __hip_bfloat16 zt[16][ZP];        // z tile

    const int t = threadIdx.x;
    const int wv = t >> 6;
    const int lane = t & 63;
    const int m = lane & 15;   // fragment row
    const int q = lane >> 4;   // fragment k-quad
    const int r = lane >> 4;   // staging: row-in-group 0..3
    const int c = lane & 15;   // staging: chunk within row
    const int base = blockIdx.x * 16;
    const int node0 = base + wv * 4;
    const int b = node0 >> 14;          // block of 16 nodes never straddles NN

    const __hip_bfloat16* xbh = xh + (size_t)b * (size_t)(NN * CC);
    const unsigned char*  xbq = xq + (size_t)b * (size_t)(NN * CC);
    __hip_bfloat16* sj = &stgj[wv][0];
    unsigned char*  sq = &stgq[wv][0];
    float*          wb16 = (float*)sq;  // 64B w-broadcast corner (aliased)

    // ---- hoisted edge indices (m-layout) + residual rows for all 4 nodes ----
    int ejv[4], eiv[4];
    __hip_bfloat162 rxv[4];
    #pragma unroll
    for (int n = 0; n < 4; ++n) {
        const int* ej = edge + (size_t)(node0 + n) * KK;
        ejv[n] = __builtin_nontemporal_load(ej + m);
        eiv[n] = __builtin_nontemporal_load(ej + (size_t)NODES * KK + m);
        const int nloc = (node0 + n) & (NN - 1);
        rxv[n] = *(const __hip_bfloat162*)(xbh + (size_t)nloc * CC + 2 * lane);
    }

    // Per-node body: stage -> scores -> softmax -> column-reduce h -> zt row.
    auto body = [&](const Rows& A, int it) {
        // ---- stage node `it` to LDS (wave-private; in-order DS) ----
        #pragma unroll
        for (int g = 0; g < 4; ++g)
            *(int2*)(sq + (g * 4 + r) * SQP + c * 8) = A.qi[g];
        #pragma unroll
        for (int g = 0; g < 4; ++g)
            *(bf16x8*)(sj + (g * 4 + r) * SP + c * 8) = A.j[g];

        // ---- fragments + scores; Xi fp8->bf16 fused into MFMA loop ----
        f32x4 acc = {0.f, 0.f, 0.f, 0.f};
        #pragma unroll
        for (int s = 0; s < 4; ++s) {
            int2 wa = *(const int2*)(sq + m * SQP + s * 32 + q * 8);
            bf16x8 bfr = *(const bf16x8*)(sj + m * SP + s * 32 + q * 8);
            acc = __builtin_amdgcn_mfma_f32_16x16x32_bf16(up8(wa), bfr, acc, 0, 0, 0);
        }

        // ---- softmax col-sum: wj for j = lane&15, replicated over q ----
        const float wj = col_weight(acc);

        // ---- h via column reduction: broadcast w, each lane fmas its own
        //      2 channels from Xj columns (sq consumed; corner aliased) ----
        if (lane < 16) wb16[lane] = wj;
        f32x4 wv0 = *(const f32x4*)&wb16[0];
        f32x4 wv1 = *(const f32x4*)&wb16[4];
        f32x4 wv2 = *(const f32x4*)&wb16[8];
        f32x4 wv3 = *(const f32x4*)&wb16[12];
        float wvv[16] = {wv0[0], wv0[1], wv0[2], wv0[3],
                         wv1[0], wv1[1], wv1[2], wv1[3],
                         wv2[0], wv2[1], wv2[2], wv2[3],
                         wv3[0], wv3[1], wv3[2], wv3[3]};
        float ax[4] = {0.f, 0.f, 0.f, 0.f};
        float ay[4] = {0.f, 0.f, 0.f, 0.f};
        const char* sjb = (const char*)sj + 4 * lane;
        #pragma unroll
        for (int j = 0; j < 16; ++j) {
            unsigned u = *(const unsigned*)(sjb + j * (SP * 2));
            float lo = __uint_as_float(u << 16);
            float hi = __uint_as_float(u & 0xffff0000u);
            ax[j & 3] = fmaf(wvv[j], lo, ax[j & 3]);
            ay[j & 3] = fmaf(wvv[j], hi, ay[j & 3]);
        }
        float hx = (ax[0] + ax[1]) + (ax[2] + ax[3]);
        float hy = (ay[0] + ay[1]) + (ay[2] + ay[3]);

        // ---- residual + cast, into the z LDS tile ----
        float2 xc = __bfloat1622float2(rxv[it]);
        const int row = wv * 4 + it;
        *(__hip_bfloat162*)(&zt[row][2 * lane]) =
            __float22bfloat162_rn(make_float2(xc.x + hx, xc.y + hy));
    };

    // ---- 2-deep prefetch, hand-peeled (distinct buffers, pure SSA) ----
    Rows A, B, C0, C1;
    gather_rows(ejv[0], eiv[0], r, c, xbh, xbq, A);
    gather_rows(ejv[1], eiv[1], r, c, xbh, xbq, B);

    gather_rows(ejv[2], eiv[2], r, c, xbh, xbq, C0);   // issue ahead of A's stage
    body(A, 0);
    gather_rows(ejv[3], eiv[3], r, c, xbh, xbq, C1);   // issue ahead of B's stage
    body(B, 1);
    body(C0, 2);
    body(C1, 3);

    __syncthreads();

    // ---- fused linear: out[16 nodes][128] = relu(zt @ W^T + b) ----
    bf16x8 zfr[4];
    #pragma unroll
    for (int s = 0; s < 4; ++s)
        zfr[s] = *(const bf16x8*)(&zt[m][s * 32 + q * 8]);

    #pragma unroll
    for (int half = 0; half < 2; ++half) {
        const int ct = wv * 2 + half;            // cout-tile 0..7
        const __hip_bfloat16* wp = wh + (size_t)(ct * 16 + m) * CC + q * 8;
        bf16x8 wfr[4];
        #pragma unroll
        for (int s = 0; s < 4; ++s)
            wfr[s] = *(const bf16x8*)(wp + s * 32);
        const float bv = bias[ct * 16 + m];
        f32x4 acc = {0.f, 0.f, 0.f, 0.f};
        #pragma unroll
        for (int s = 0; s < 4; ++s)
            acc = __builtin_amdgcn_mfma_f32_16x16x32_bf16(zfr[s], wfr[s], acc, 0, 0, 0);
        // C/D layout: col = lane&15 = cout-in-tile, row = q*4+i = node-in-tile
        float* op = out + (size_t)(base + q * 4) * COUT + ct * 16 + m;
        #pragma unroll
        for (int i = 0; i < 4; ++i)
            op[(size_t)i * COUT] = fmaxf(acc[i] + bv, 0.f);
    }
}

extern "C" void kernel_launch(void* const* d_in, const int* in_sizes, int n_in,
                              void* d_out, int out_size, void* d_ws, size_t ws_size,
                              hipStream_t stream) {
    const float* x    = (const float*)d_in[0];
    const int*   edge = (const int*)d_in[1];
    const float* W    = (const float*)d_in[2];
    const float* bias = (const float*)d_in[3];
    float* out = (float*)d_out;
    __hip_bfloat16* xh = (__hip_bfloat16*)d_ws;                              // 8 MB
    unsigned char*  xq = (unsigned char*)d_ws + 8 * 1024 * 1024;             // 4 MB
    __hip_bfloat16* wh = (__hip_bfloat16*)((char*)d_ws + 12 * 1024 * 1024);  // 32 KB

    cast_x<<<XBLK + (COUT * CC) / (256 * 8), 256, 0, stream>>>(x, xh, xq, W, wh);
    attn_fused<<<NODES / 16, 256, 0, stream>>>(xh, xq, edge, wh, bias, out);
}